// Round 1
// baseline (9463.659 us; speedup 1.0000x reference)
//
#include <hip/hip_runtime.h>

#define Bb 256
#define Tt 512
#define NF 64
#define H1 256
#define H2 128
#define K1 (NF + H1)   // 320
#define K2 (H1 + H2)   // 384
#define R1 (4 * H1)    // 1024
#define R2 (4 * H2)    // 512
#define NB1 256        // (H1/4) * (Bb/64)
#define NB2 128        // (H2/4) * (Bb/64)

// workspace offsets, in floats
#define OFF_WT1 0
#define OFF_B1  (OFF_WT1 + K1 * R1)        // 327680
#define OFF_WT2 (OFF_B1 + R1)              // 328704
#define OFF_B2  (OFF_WT2 + K2 * R2)        // 525312
#define OFF_H1B (OFF_B2 + R2)              // 525824
#define OFF_C1  (OFF_H1B + 2 * H1 * Bb)    // 656896
#define OFF_H2B (OFF_C1 + H1 * Bb)         // 722432
#define OFF_C2  (OFF_H2B + 2 * H2 * Bb)    // 787968
#define OFF_XT  (OFF_C2 + H2 * Bb)         // 820736
#define WS_FLOATS_XT (OFF_XT + (size_t)Tt * NF * Bb)

__device__ __forceinline__ float sigf(float x) {
    return 1.0f / (1.0f + __expf(-x));
}
__device__ __forceinline__ float tanhfast(float x) {
    // 2/(1+e^{-2x}) - 1 ; correct limits at +/-inf via expf
    return 2.0f / (1.0f + __expf(-2.0f * x)) - 1.0f;
}

// Build transposed/fused weights: Wt1[k][r] (k<NF from Wih1, else Whh1), biases summed.
__global__ __launch_bounds__(256) void prep_kernel(
    const float* __restrict__ Wih1, const float* __restrict__ Whh1,
    const float* __restrict__ bih1, const float* __restrict__ bhh1,
    const float* __restrict__ Wih2, const float* __restrict__ Whh2,
    const float* __restrict__ bih2, const float* __restrict__ bhh2,
    float* __restrict__ Wt1, float* __restrict__ b1s,
    float* __restrict__ Wt2, float* __restrict__ b2s)
{
    const int stride = gridDim.x * blockDim.x;
    const int i0 = blockIdx.x * blockDim.x + threadIdx.x;
    for (int idx = i0; idx < K1 * R1; idx += stride) {
        int k = idx / R1, r = idx - k * R1;
        Wt1[idx] = (k < NF) ? Wih1[r * NF + k] : Whh1[r * H1 + (k - NF)];
    }
    for (int idx = i0; idx < K2 * R2; idx += stride) {
        int k = idx / R2, r = idx - k * R2;
        Wt2[idx] = (k < H1) ? Wih2[r * H1 + k] : Whh2[r * H2 + (k - H1)];
    }
    for (int idx = i0; idx < R1; idx += stride) b1s[idx] = bih1[idx] + bhh1[idx];
    for (int idx = i0; idx < R2; idx += stride) b2s[idx] = bih2[idx] + bhh2[idx];
}

// xT[t][k][b] = x[b][t][k]  (one block per (t, 64-batch tile))
__global__ __launch_bounds__(256) void xtrans_kernel(
    const float* __restrict__ x, float* __restrict__ xT)
{
    __shared__ float tile[64][65];
    const int t  = blockIdx.x >> 2;
    const int b0 = (blockIdx.x & 3) * 64;
    for (int i = threadIdx.x; i < 64 * 64; i += 256) {
        int k = i & 63, brow = i >> 6;
        tile[brow][k] = x[((size_t)(b0 + brow) * Tt + t) * NF + k];
    }
    __syncthreads();
    for (int i = threadIdx.x; i < 64 * 64; i += 256) {
        int b = i & 63, k = i >> 6;
        xT[((size_t)t * NF + k) * Bb + b0 + b] = tile[b][k];
    }
}

// One time step: layer-1 computes step t (t<Tt), layer-2 computes step t-1 (t>=1).
__global__ __launch_bounds__(256) void step_kernel(
    int t,
    const float* __restrict__ x, const float* __restrict__ xT, int use_xT,
    const float* __restrict__ Wt1, const float* __restrict__ b1s,
    const float* __restrict__ Wt2, const float* __restrict__ b2s,
    float* __restrict__ h1buf, float* __restrict__ c1,
    float* __restrict__ h2buf, float* __restrict__ c2,
    float* __restrict__ out)
{
    __shared__ float act[4][4][64];
    __shared__ float hshare[4][64];

    const int tid  = threadIdx.x;
    const int wave = tid >> 6;
    const int lane = tid & 63;
    const int bid  = blockIdx.x;

    if (bid < NB1) {
        if (t >= Tt) return;
        // ---- layer 1, step t ----
        const int u0 = (bid >> 2) * 4;
        const int b0 = (bid & 3) * 64;
        const int b  = b0 + lane;
        const float* h1prev = h1buf + (size_t)(t & 1) * (H1 * Bb);
        float*       h1next = h1buf + (size_t)((t + 1) & 1) * (H1 * Bb);
        const int wbase = __builtin_amdgcn_readfirstlane(wave * H1 + u0);

        float4 bv = *(const float4*)(b1s + wbase);
        float acc0 = bv.x, acc1 = bv.y, acc2 = bv.z, acc3 = bv.w;

        const float* wp = Wt1 + wbase;
        if (use_xT) {
            const float* xc = xT + (size_t)t * NF * Bb + b;
            #pragma unroll 8
            for (int k = 0; k < NF; ++k) {
                const float xv = xc[k * Bb];
                const float4 wv = *(const float4*)(wp + (size_t)k * R1);
                acc0 = fmaf(wv.x, xv, acc0);
                acc1 = fmaf(wv.y, xv, acc1);
                acc2 = fmaf(wv.z, xv, acc2);
                acc3 = fmaf(wv.w, xv, acc3);
            }
        } else {
            const float* xrow = x + (size_t)b * (Tt * NF) + (size_t)t * NF;
            #pragma unroll 8
            for (int k = 0; k < NF; ++k) {
                const float xv = xrow[k];
                const float4 wv = *(const float4*)(wp + (size_t)k * R1);
                acc0 = fmaf(wv.x, xv, acc0);
                acc1 = fmaf(wv.y, xv, acc1);
                acc2 = fmaf(wv.z, xv, acc2);
                acc3 = fmaf(wv.w, xv, acc3);
            }
        }
        {
            const float* hp  = h1prev + b;
            const float* wph = Wt1 + (size_t)NF * R1 + wbase;
            #pragma unroll 8
            for (int k = 0; k < H1; ++k) {
                const float hv = hp[k * Bb];
                const float4 wv = *(const float4*)(wph + (size_t)k * R1);
                acc0 = fmaf(wv.x, hv, acc0);
                acc1 = fmaf(wv.y, hv, acc1);
                acc2 = fmaf(wv.z, hv, acc2);
                acc3 = fmaf(wv.w, hv, acc3);
            }
        }
        if (wave == 2) {
            acc0 = tanhfast(acc0); acc1 = tanhfast(acc1);
            acc2 = tanhfast(acc2); acc3 = tanhfast(acc3);
        } else {
            acc0 = sigf(acc0); acc1 = sigf(acc1);
            acc2 = sigf(acc2); acc3 = sigf(acc3);
        }
        act[wave][0][lane] = acc0;
        act[wave][1][lane] = acc1;
        act[wave][2][lane] = acc2;
        act[wave][3][lane] = acc3;
        __syncthreads();
        {
            const int ul = wave;            // 4 units x 64 lanes = 256 threads
            const float iv = act[0][ul][lane];
            const float fv = act[1][ul][lane];
            const float gv = act[2][ul][lane];
            const float ov = act[3][ul][lane];
            const int idx = (u0 + ul) * Bb + b0 + lane;
            float c = c1[idx];
            c = fv * c + iv * gv;
            c1[idx] = c;
            h1next[idx] = ov * tanhfast(c);
        }
    } else {
        if (t < 1) return;
        // ---- layer 2, step s = t-1 ----
        const int s   = t - 1;
        const int bid2 = bid - NB1;
        const int u0 = (bid2 >> 2) * 4;
        const int b0 = (bid2 & 3) * 64;
        const int b  = b0 + lane;
        const float* h1cur  = h1buf + (size_t)(t & 1) * (H1 * Bb);
        const float* h2prev = h2buf + (size_t)((t + 1) & 1) * (H2 * Bb);
        float*       h2next = h2buf + (size_t)(t & 1) * (H2 * Bb);
        const int wbase = __builtin_amdgcn_readfirstlane(wave * H2 + u0);

        float4 bv = *(const float4*)(b2s + wbase);
        float acc0 = bv.x, acc1 = bv.y, acc2 = bv.z, acc3 = bv.w;

        {
            const float* hp = h1cur + b;
            const float* wp = Wt2 + wbase;
            #pragma unroll 8
            for (int k = 0; k < H1; ++k) {
                const float hv = hp[k * Bb];
                const float4 wv = *(const float4*)(wp + (size_t)k * R2);
                acc0 = fmaf(wv.x, hv, acc0);
                acc1 = fmaf(wv.y, hv, acc1);
                acc2 = fmaf(wv.z, hv, acc2);
                acc3 = fmaf(wv.w, hv, acc3);
            }
        }
        {
            const float* hp = h2prev + b;
            const float* wp = Wt2 + (size_t)H1 * R2 + wbase;
            #pragma unroll 8
            for (int k = 0; k < H2; ++k) {
                const float hv = hp[k * Bb];
                const float4 wv = *(const float4*)(wp + (size_t)k * R2);
                acc0 = fmaf(wv.x, hv, acc0);
                acc1 = fmaf(wv.y, hv, acc1);
                acc2 = fmaf(wv.z, hv, acc2);
                acc3 = fmaf(wv.w, hv, acc3);
            }
        }
        if (wave == 2) {
            acc0 = tanhfast(acc0); acc1 = tanhfast(acc1);
            acc2 = tanhfast(acc2); acc3 = tanhfast(acc3);
        } else {
            acc0 = sigf(acc0); acc1 = sigf(acc1);
            acc2 = sigf(acc2); acc3 = sigf(acc3);
        }
        act[wave][0][lane] = acc0;
        act[wave][1][lane] = acc1;
        act[wave][2][lane] = acc2;
        act[wave][3][lane] = acc3;
        __syncthreads();
        {
            const int ul = wave;
            const float iv = act[0][ul][lane];
            const float fv = act[1][ul][lane];
            const float gv = act[2][ul][lane];
            const float ov = act[3][ul][lane];
            const int idx = (u0 + ul) * Bb + b0 + lane;
            float c = c2[idx];
            c = fv * c + iv * gv;
            c2[idx] = c;
            const float h = ov * tanhfast(c);
            h2next[idx] = h;
            hshare[ul][lane] = h;
        }
        __syncthreads();
        if (tid < 64) {
            const int bb = b0 + tid;
            float4 hv = make_float4(hshare[0][tid], hshare[1][tid],
                                    hshare[2][tid], hshare[3][tid]);
            *(float4*)(out + ((size_t)bb * Tt + s) * H2 + u0) = hv;
            if (s == Tt - 1) {
                *(float4*)(out + (size_t)Bb * Tt * H2 + (size_t)bb * H2 + u0) = hv;
            }
        }
    }
}

extern "C" void kernel_launch(void* const* d_in, const int* in_sizes, int n_in,
                              void* d_out, int out_size, void* d_ws, size_t ws_size,
                              hipStream_t stream) {
    const float* x    = (const float*)d_in[0];
    const float* Wih1 = (const float*)d_in[1];
    const float* Whh1 = (const float*)d_in[2];
    const float* bih1 = (const float*)d_in[3];
    const float* bhh1 = (const float*)d_in[4];
    const float* Wih2 = (const float*)d_in[5];
    const float* Whh2 = (const float*)d_in[6];
    const float* bih2 = (const float*)d_in[7];
    const float* bhh2 = (const float*)d_in[8];
    float* ws  = (float*)d_ws;
    float* out = (float*)d_out;

    float* Wt1 = ws + OFF_WT1;
    float* b1s = ws + OFF_B1;
    float* Wt2 = ws + OFF_WT2;
    float* b2s = ws + OFF_B2;
    float* h1b = ws + OFF_H1B;
    float* c1  = ws + OFF_C1;
    float* h2b = ws + OFF_H2B;
    float* c2  = ws + OFF_C2;
    float* xT  = ws + OFF_XT;

    const int use_xT = (ws_size >= WS_FLOATS_XT * sizeof(float)) ? 1 : 0;

    prep_kernel<<<512, 256, 0, stream>>>(Wih1, Whh1, bih1, bhh1,
                                         Wih2, Whh2, bih2, bhh2,
                                         Wt1, b1s, Wt2, b2s);
    // zero h/c state (contiguous region OFF_H1B .. OFF_XT)
    hipMemsetAsync((void*)h1b, 0, (size_t)(OFF_XT - OFF_H1B) * sizeof(float), stream);
    if (use_xT) {
        xtrans_kernel<<<Tt * (Bb / 64), 256, 0, stream>>>(x, xT);
    }
    for (int t = 0; t <= Tt; ++t) {
        step_kernel<<<NB1 + NB2, 256, 0, stream>>>(
            t, x, xT, use_xT, Wt1, b1s, Wt2, b2s, h1b, c1, h2b, c2, out);
    }
}